// Round 13
// baseline (325.939 us; speedup 1.0000x reference)
//
#include <hip/hip_runtime.h>
#include <hip/hip_fp16.h>
#include <cstdint>
#include <cstddef>

// ---------------------------------------------------------------------------
// GCN 3-layer forward on MI355X.
// R3: layer 1 aggregates x at D=64 (A(XW)=(AX)W).
// R5/R9: all node-feature buffers fp16. agg128 at compulsory L2-fill floor
//   (FETCH 189MB == 8 XCDs x 86.5% x 25.6MB + csr). agg64 measured 189MB vs
//   ~96MB compulsory -> 2x capacity misses = last addressable traffic.
// R10: MFMA f16 GEMMs. R12: scale folded into build tail.
// R13: per-node adjacency sorted ascending by src (insertion sort in
//   k_build_bucket tail). All waves then walk src monotonically ->
//   concurrent working set shrinks to an L2-resident window -> agg64
//   capacity misses become hits. Semantically free (sum order arbitrary).
// ---------------------------------------------------------------------------

#define CHUNK 4096    // edges per partition block
#define BSHIFT 7      // bucket = dst >> 7  (128 nodes / bucket)
#define BSZ 128

typedef _Float16 half8 __attribute__((ext_vector_type(8)));
typedef float floatx4 __attribute__((ext_vector_type(4)));

__device__ __forceinline__ int eload(const int* ei, int elem, int is64) {
  return is64 ? ei[2 * elem] : ei[elem];
}

// Detect int64 vs int32 storage: for int64, high words of the first 1024
// elements are all zero (values in [0, N) < 2^31).
__global__ void k_detect(const int* __restrict__ ei, int* __restrict__ flag) {
  __shared__ int sh[256];
  int tid = threadIdx.x;
  int o = 0;
  for (int i = tid; i < 1024; i += 256) o |= ei[2 * i + 1];
  sh[tid] = o;
  __syncthreads();
  for (int s = 128; s > 0; s >>= 1) {
    if (tid < s) sh[tid] |= sh[tid + s];
    __syncthreads();
  }
  if (tid == 0) *flag = (sh[0] == 0) ? 1 : 0;
}

// per-chunk LDS histogram over dst buckets; hist is bucket-major [P][NBLK]
__global__ __launch_bounds__(256) void k_hist(const int* __restrict__ ei,
                                              int* __restrict__ hist, int E,
                                              int N, int NBLK,
                                              const int* __restrict__ flag) {
  __shared__ int lh[1024];
  int tid = threadIdx.x;
  int P = (N + BSZ - 1) >> BSHIFT;
  for (int i = tid; i < P; i += 256) lh[i] = 0;
  __syncthreads();
  int is64 = *flag;
  int e0 = blockIdx.x * CHUNK;
  int e1 = min(e0 + CHUNK, E);
  for (int e = e0 + tid; e < e1; e += 256) {
    int d = eload(ei, E + e, is64);
    atomicAdd(&lh[d >> BSHIFT], 1);
  }
  __syncthreads();
  for (int b = tid; b < P; b += 256) hist[b * NBLK + blockIdx.x] = lh[b];
}

// ---- generic 2-level exclusive scan (1024 elems / block) ----
__global__ __launch_bounds__(256) void k_scanA(const int* __restrict__ in,
                                               int* __restrict__ out,
                                               int* __restrict__ bsum, int n) {
  __shared__ int sh[256];
  int tid = threadIdx.x;
  int base = blockIdx.x * 1024 + tid * 4;
  int v0 = (base + 0 < n) ? in[base + 0] : 0;
  int v1 = (base + 1 < n) ? in[base + 1] : 0;
  int v2 = (base + 2 < n) ? in[base + 2] : 0;
  int v3 = (base + 3 < n) ? in[base + 3] : 0;
  int tsum = v0 + v1 + v2 + v3;
  sh[tid] = tsum;
  __syncthreads();
  for (int o = 1; o < 256; o <<= 1) {
    int x = (tid >= o) ? sh[tid - o] : 0;
    __syncthreads();
    sh[tid] += x;
    __syncthreads();
  }
  int excl = sh[tid] - tsum;
  if (base + 0 < n) out[base + 0] = excl;
  if (base + 1 < n) out[base + 1] = excl + v0;
  if (base + 2 < n) out[base + 2] = excl + v0 + v1;
  if (base + 3 < n) out[base + 3] = excl + v0 + v1 + v2;
  if (tid == 255) bsum[blockIdx.x] = sh[255];
}

// exclusive scan of up to 1024 block sums, in place (4 per thread)
__global__ __launch_bounds__(256) void k_scanB(int* __restrict__ bsum, int NB) {
  __shared__ int sh[256];
  int tid = threadIdx.x;
  int base = tid * 4;
  int v0 = (base + 0 < NB) ? bsum[base + 0] : 0;
  int v1 = (base + 1 < NB) ? bsum[base + 1] : 0;
  int v2 = (base + 2 < NB) ? bsum[base + 2] : 0;
  int v3 = (base + 3 < NB) ? bsum[base + 3] : 0;
  int tsum = v0 + v1 + v2 + v3;
  sh[tid] = tsum;
  __syncthreads();
  for (int o = 1; o < 256; o <<= 1) {
    int x = (tid >= o) ? sh[tid - o] : 0;
    __syncthreads();
    sh[tid] += x;
    __syncthreads();
  }
  int excl = sh[tid] - tsum;
  if (base + 0 < NB) bsum[base + 0] = excl;
  if (base + 1 < NB) bsum[base + 1] = excl + v0;
  if (base + 2 < NB) bsum[base + 2] = excl + v0 + v1;
  if (base + 3 < NB) bsum[base + 3] = excl + v0 + v1 + v2;
}

__global__ __launch_bounds__(256) void k_scanC(int* __restrict__ out,
                                               const int* __restrict__ bsum,
                                               int n, int total) {
  int i = blockIdx.x * 256 + threadIdx.x;
  if (i == 0) out[n] = total;
  if (i < n) out[i] += bsum[i >> 10];
}

// scatter edges into bucket-partitioned `pairs`, packed (src<<BSHIFT)|dst_lo.
__global__ __launch_bounds__(256) void k_scatter(const int* __restrict__ ei,
                                                 const int* __restrict__ histoff,
                                                 int* __restrict__ pairs, int E,
                                                 int N, int NBLK,
                                                 const int* __restrict__ flag) {
  __shared__ int lcur[1024];
  int tid = threadIdx.x;
  int P = (N + BSZ - 1) >> BSHIFT;
  for (int b = tid; b < P; b += 256)
    lcur[b] = histoff[b * NBLK + blockIdx.x];
  __syncthreads();
  int is64 = *flag;
  int e0 = blockIdx.x * CHUNK;
  int e1 = min(e0 + CHUNK, E);
  for (int e = e0 + tid; e < e1; e += 256) {
    int s = eload(ei, e, is64);
    int d = eload(ei, E + e, is64);
    int pos = atomicAdd(&lcur[d >> BSHIFT], 1);
    pairs[pos] = (s << BSHIFT) | (d & (BSZ - 1));
  }
}

// ---------------------------------------------------------------------------
// Fused per-bucket build: degree count -> 128-wide local exclusive scan ->
// off[] + dis[] -> CSR fill -> per-node src-sort (insertion) ->
// (folded) xsh = fp16(x * dis). Offsets bucket-local: base = histoff[b*NBLK].
// ---------------------------------------------------------------------------
__global__ __launch_bounds__(256) void k_build_bucket(
    const int* __restrict__ pairs, const int* __restrict__ histoff,
    int* __restrict__ off, float* __restrict__ dis, int* __restrict__ csr,
    const float* __restrict__ x, __half* __restrict__ xsh, int E, int N,
    int NBLK, int P) {
  __shared__ int lc[BSZ];
  __shared__ int lscan[BSZ];
  __shared__ int lcur[BSZ];
  __shared__ float ldis[BSZ];
  int tid = threadIdx.x;
  int b = blockIdx.x;
  if (tid < BSZ) lc[tid] = 0;
  __syncthreads();
  int s0 = histoff[b * NBLK];
  int s1 = histoff[(b + 1) * NBLK];
  for (int i = s0 + tid; i < s1; i += 256)
    atomicAdd(&lc[pairs[i] & (BSZ - 1)], 1);
  __syncthreads();
  if (tid < BSZ) lscan[tid] = lc[tid];
  __syncthreads();
#pragma unroll
  for (int o = 1; o < BSZ; o <<= 1) {
    int v = 0;
    if (tid < BSZ && tid >= o) v = lscan[tid - o];
    __syncthreads();
    if (tid < BSZ) lscan[tid] += v;
    __syncthreads();
  }
  int node = (b << BSHIFT) + tid;
  int seg_beg = 0, seg_deg = 0;
  if (tid < BSZ) {
    seg_beg = s0 + lscan[tid] - lc[tid];  // exclusive
    seg_deg = lc[tid];
    lcur[tid] = seg_beg;
    float d = rsqrtf((float)(seg_deg + 1));  // +1 self loop
    ldis[tid] = d;
    if (node < N) {
      off[node] = seg_beg;
      dis[node] = d;
    }
  }
  if (b == P - 1 && tid == 0) off[N] = E;
  __syncthreads();
  // CSR fill
  for (int i = s0 + tid; i < s1; i += 256) {
    int pk = pairs[i];
    int pos = atomicAdd(&lcur[pk & (BSZ - 1)], 1);
    csr[pos] = pk >> BSHIFT;
  }
  __syncthreads();
  // per-node ascending src sort (insertion; segment is L2-local).
  // Makes every agg wave walk src monotonically -> concurrent src window
  // stays L2-resident -> agg64 capacity misses become hits.
  if (tid < BSZ && node < N) {
    for (int i = 1; i < seg_deg; i++) {
      int key = csr[seg_beg + i];
      int j = i - 1;
      while (j >= 0 && csr[seg_beg + j] > key) {
        csr[seg_beg + j + 1] = csr[seg_beg + j];
        j--;
      }
      csr[seg_beg + j + 1] = key;
    }
  }
  // folded scale: xsh[row] = fp16(x[row]*dis[row]) for this bucket's rows
  for (int t = tid; t < BSZ * 16; t += 256) {
    int rl = t >> 4, q = t & 15;
    int row = (b << BSHIFT) + rl;
    if (row < N) {
      float d = ldis[rl];
      float4 v = *(const float4*)&x[(size_t)row * 64 + q * 4];
      union { uint2 u; __half2 h[2]; } pk;
      pk.h[0] = __floats2half2_rn(v.x * d, v.y * d);
      pk.h[1] = __floats2half2_rn(v.z * d, v.w * d);
      *(uint2*)&xsh[(size_t)row * 64 + q * 4] = pk.u;
    }
  }
}

__device__ __forceinline__ float gelu_exact(float v) {
  return 0.5f * v * (1.0f + erff(v * 0.70710678118654752440f));
}

// ---------------------------------------------------------------------------
// MFMA GEMM (fp16 in, fp32 acc, fp16 out). 256 thr = 4 waves x 16 rows.
// W staged fp16 fragment-major in LDS (frag*1KB + lane*16B, conflict-free
// ds_read_b128). A frags from global. Layouts per m89/m97:
// A row=l&15, k=8*(l>>4)+e; D col=l&15, row=4*(l>>4)+reg.
// EPI=0: out = (X@W)*dis[row]; EPI=1: out = gelu((X@W)+bias).
// ---------------------------------------------------------------------------
template <int K, int M, int EPI>
__global__ __launch_bounds__(256) void k_gemm5(
    const __half* __restrict__ X, const float* __restrict__ W,
    const float* __restrict__ dis, const float* __restrict__ bias,
    __half* __restrict__ G, int N) {
  constexpr int NT = M / 16;   // n-tiles
  constexpr int KK = K / 32;   // k-steps
  __shared__ _Float16 WtL[M * K];  // fragment-major

  int tid = threadIdx.x;
  for (int t = tid; t < M * K / 8; t += 256) {
    int l = t & 63;
    int fid = t >> 6;
    int nt = fid / KK, kk = fid % KK;
    int n = nt * 16 + (l & 15);
    int k0 = kk * 32 + (l >> 4) * 8;
    half8 h;
#pragma unroll
    for (int e = 0; e < 8; e++)
      h[e] = (_Float16)W[(size_t)(k0 + e) * M + n];
    *(half8*)&WtL[(size_t)t * 8] = h;
  }
  __syncthreads();

  int wave = tid >> 6, l = tid & 63;
  int lr = l & 15, lg = l >> 4;
  int row0 = blockIdx.x * 64 + wave * 16;

  half8 a[KK];
  {
    int row = min(row0 + lr, N - 1);
    const __half* xp = X + (size_t)row * K + lg * 8;
#pragma unroll
    for (int kk = 0; kk < KK; kk++)
      a[kk] = *(const half8*)(xp + kk * 32);
  }

  floatx4 acc[NT];
#pragma unroll
  for (int nt = 0; nt < NT; nt++) acc[nt] = {0.f, 0.f, 0.f, 0.f};

#pragma unroll
  for (int nt = 0; nt < NT; nt++) {
#pragma unroll
    for (int kk = 0; kk < KK; kk++) {
      half8 b = *(const half8*)&WtL[(size_t)((nt * KK + kk) * 64 + l) * 8];
      acc[nt] = __builtin_amdgcn_mfma_f32_16x16x32_f16(a[kk], b, acc[nt], 0, 0, 0);
    }
  }

#pragma unroll
  for (int r = 0; r < 4; r++) {
    int row = row0 + lg * 4 + r;
    if (row < N) {
      float dd = (EPI == 0) ? dis[row] : 0.f;
#pragma unroll
      for (int nt = 0; nt < NT; nt++) {
        int col = nt * 16 + lr;
        float v = acc[nt][r];
        if constexpr (EPI == 0) v *= dd;
        else v = gelu_exact(v + bias[col]);
        G[(size_t)row * M + col] = __float2half(v);
      }
    }
  }
}

__device__ __forceinline__ void acc8(float* a, uint4 r) {
  const __half2* h = reinterpret_cast<const __half2*>(&r);
#pragma unroll
  for (int q = 0; q < 4; q++) {
    float2 f = __half22float2(h[q]);
    a[2 * q] += f.x;
    a[2 * q + 1] += f.y;
  }
}

// ---------------------------------------------------------------------------
// fp16-table aggregation: 8 halves (16B) per lane, LPN = D/8 lanes per node,
// NPW = 64/LPN nodes per wave. fp32 accumulate. F16OUT: fp16 output buffer.
// ---------------------------------------------------------------------------
template <int D, bool HAS_BIAS, bool HAS_GELU, bool F16OUT>
__global__ __launch_bounds__(256) void k_agg(
    const __half* __restrict__ g, const int* __restrict__ off,
    const int* __restrict__ csr, const float* __restrict__ dis,
    const float* __restrict__ bias, void* __restrict__ outv, int N) {
  constexpr int LPN = D / 8;     // lanes per node (16B of halves each)
  constexpr int NPW = 64 / LPN;  // nodes per wave
  int wave = (blockIdx.x * 256 + threadIdx.x) >> 6;
  int lane = threadIdx.x & 63;
  int sub = lane / LPN;
  int sl = lane % LPN;
  int node = wave * NPW + sub;
  if (node >= N) return;
  const uint4* G16 = (const uint4*)g;
  float a[8];
#pragma unroll
  for (int q = 0; q < 8; q++) a[q] = 0.f;
  acc8(a, G16[(size_t)node * LPN + sl]);  // self loop
  int beg = off[node], end = off[node + 1];
  int j = beg;
  for (; j + 4 <= end; j += 4) {
    int s0 = csr[j], s1 = csr[j + 1], s2 = csr[j + 2], s3 = csr[j + 3];
    uint4 r0 = G16[(size_t)s0 * LPN + sl];
    uint4 r1 = G16[(size_t)s1 * LPN + sl];
    uint4 r2 = G16[(size_t)s2 * LPN + sl];
    uint4 r3 = G16[(size_t)s3 * LPN + sl];
    acc8(a, r0);
    acc8(a, r1);
    acc8(a, r2);
    acc8(a, r3);
  }
  for (; j < end; j++) acc8(a, G16[(size_t)csr[j] * LPN + sl]);
  float dd = dis[node];
  int c0 = sl * 8;
  float v[8];
#pragma unroll
  for (int q = 0; q < 8; q++) v[q] = a[q] * dd;
  if constexpr (HAS_BIAS) {
    float4 b0 = *(const float4*)&bias[c0];
    float4 b1 = *(const float4*)&bias[c0 + 4];
    v[0] += b0.x; v[1] += b0.y; v[2] += b0.z; v[3] += b0.w;
    v[4] += b1.x; v[5] += b1.y; v[6] += b1.z; v[7] += b1.w;
  }
  if constexpr (HAS_GELU) {
#pragma unroll
    for (int q = 0; q < 8; q++) v[q] = gelu_exact(v[q]);
  }
  if constexpr (F16OUT) {
    union { uint4 u; __half2 h[4]; } pk;
#pragma unroll
    for (int q = 0; q < 4; q++)
      pk.h[q] = __floats2half2_rn(v[2 * q], v[2 * q + 1]);
    *(uint4*)&((__half*)outv)[(size_t)node * D + c0] = pk.u;
  } else {
    float* out = (float*)outv;
    float4 o0 = {v[0], v[1], v[2], v[3]};
    float4 o1 = {v[4], v[5], v[6], v[7]};
    *(float4*)&out[(size_t)node * D + c0] = o0;
    *(float4*)&out[(size_t)node * D + c0 + 4] = o1;
  }
}

extern "C" void kernel_launch(void* const* d_in, const int* in_sizes, int n_in,
                              void* d_out, int out_size, void* d_ws,
                              size_t ws_size, hipStream_t stream) {
  const float* x = (const float*)d_in[0];
  const int* ei = (const int*)d_in[1];
  const float* W1 = (const float*)d_in[2];
  const float* b1 = (const float*)d_in[3];
  const float* W2 = (const float*)d_in[4];
  const float* b2 = (const float*)d_in[5];
  const float* W3 = (const float*)d_in[6];
  const float* b3 = (const float*)d_in[7];
  float* out = (float*)d_out;

  const int N = in_sizes[0] / 64;
  const int E = in_sizes[1] / 2;

  const int NBLK = (E + CHUNK - 1) / CHUNK;
  const int P = (N + BSZ - 1) >> BSHIFT;
  const int HT = P * NBLK;

  char* p = (char*)d_ws;
  auto alloc = [&](size_t bytes) {
    char* r = p;
    p += (bytes + 255) & ~(size_t)255;
    return r;
  };
  float* dis = (float*)alloc((size_t)N * 4);
  int* off = (int*)alloc((size_t)(N + 1) * 4);
  int* bsumH = (int*)alloc(4096);
  int* flag = (int*)alloc(256);
  int* hist = (int*)alloc((size_t)(HT + 1) * 4);
  int* histoff = (int*)alloc((size_t)(HT + 1) * 4);
  int* pairs = (int*)alloc((size_t)E * 4);
  int* csr = (int*)alloc((size_t)E * 4);
  __half* xsh = (__half*)alloc((size_t)N * 64 * 2);   // gather table L1
  __half* Xa_h = (__half*)alloc((size_t)N * 64 * 2);  // agg1 out / gemm1 in
  __half* h1_h = (__half*)alloc((size_t)N * 128 * 2); // gemm1 out / gemm2 in
  __half* gh = (__half*)alloc((size_t)N * 128 * 2);   // gemm2 out = table L2
  __half* h2_h = (__half*)alloc((size_t)N * 128 * 2); // agg2 out / gemm3 in
  __half* gh2 = (__half*)alloc((size_t)N * 64 * 2);   // gemm3 out = table L3

  const int NBH = (HT + 1023) / 1024;  // <= 1024 supported by k_scanB

  k_detect<<<1, 256, 0, stream>>>(ei, flag);
  k_hist<<<NBLK, 256, 0, stream>>>(ei, hist, E, N, NBLK, flag);
  k_scanA<<<NBH, 256, 0, stream>>>(hist, histoff, bsumH, HT);
  k_scanB<<<1, 256, 0, stream>>>(bsumH, NBH);
  k_scanC<<<(HT + 255) / 256, 256, 0, stream>>>(histoff, bsumH, HT, E);
  k_scatter<<<NBLK, 256, 0, stream>>>(ei, histoff, pairs, E, N, NBLK, flag);
  k_build_bucket<<<P, 256, 0, stream>>>(pairs, histoff, off, dis, csr, x, xsh,
                                        E, N, NBLK, P);

  const int gemm_blocks = (N + 63) / 64;    // 64 rows / block
  const int agg128_blocks = (N + 15) / 16;  // 4 nodes/wave, 4 waves/block
  const int agg64_blocks = (N + 31) / 32;   // 8 nodes/wave, 4 waves/block

  // layer 1 (swapped): Xa = agg(xsh); h1 = gelu(Xa@W1 + b1)
  k_agg<64, false, false, true><<<agg64_blocks, 256, 0, stream>>>(
      xsh, off, csr, dis, nullptr, (void*)Xa_h, N);
  k_gemm5<64, 128, 1><<<gemm_blocks, 256, 0, stream>>>(Xa_h, W1, nullptr, b1,
                                                       h1_h, N);
  // layer 2: g = fp16((h1@W2)*dis); h2 = fp16(gelu(agg(g) + b2))
  k_gemm5<128, 128, 0><<<gemm_blocks, 256, 0, stream>>>(h1_h, W2, dis, nullptr,
                                                        gh, N);
  k_agg<128, true, true, true><<<agg128_blocks, 256, 0, stream>>>(
      gh, off, csr, dis, b2, (void*)h2_h, N);
  // layer 3: g = fp16((h2@W3)*dis); out = agg(g) + b3 (fp32)
  k_gemm5<128, 64, 0><<<gemm_blocks, 256, 0, stream>>>(h2_h, W3, dis, nullptr,
                                                       gh2, N);
  k_agg<64, true, false, false><<<agg64_blocks, 256, 0, stream>>>(
      gh2, off, csr, dis, b3, (void*)out, N);
}

// Round 14
// 233.544 us; speedup vs baseline: 1.3956x; 1.3956x over previous
//
#include <hip/hip_runtime.h>
#include <hip/hip_fp16.h>
#include <cstdint>
#include <cstddef>

// ---------------------------------------------------------------------------
// GCN 3-layer forward on MI355X.  (R14 = rollback to verified R12 state)
// R3: layer 1 aggregates x at D=64 (A(XW)=(AX)W).
// R5/R9: all node-feature buffers fp16. agg128 at compulsory L2-fill floor
//   (FETCH 189MB == 8 XCDs x 86.5% x 25.6MB + csr at ~3.4TB/s fill).
// R10: MFMA f16 GEMMs. R12: scale folded into build tail.
// R13 (reverted): exact src-sort of adjacency gained only ~20us in aggs but
//   cost ~112us (serial insertion sort); cheap variants (bitonic/radix)
//   cost what they save -> locality family closed out. This is the floor.
// ---------------------------------------------------------------------------

#define CHUNK 4096    // edges per partition block
#define BSHIFT 7      // bucket = dst >> 7  (128 nodes / bucket)
#define BSZ 128

typedef _Float16 half8 __attribute__((ext_vector_type(8)));
typedef float floatx4 __attribute__((ext_vector_type(4)));

__device__ __forceinline__ int eload(const int* ei, int elem, int is64) {
  return is64 ? ei[2 * elem] : ei[elem];
}

// Detect int64 vs int32 storage: for int64, high words of the first 1024
// elements are all zero (values in [0, N) < 2^31).
__global__ void k_detect(const int* __restrict__ ei, int* __restrict__ flag) {
  __shared__ int sh[256];
  int tid = threadIdx.x;
  int o = 0;
  for (int i = tid; i < 1024; i += 256) o |= ei[2 * i + 1];
  sh[tid] = o;
  __syncthreads();
  for (int s = 128; s > 0; s >>= 1) {
    if (tid < s) sh[tid] |= sh[tid + s];
    __syncthreads();
  }
  if (tid == 0) *flag = (sh[0] == 0) ? 1 : 0;
}

// per-chunk LDS histogram over dst buckets; hist is bucket-major [P][NBLK]
__global__ __launch_bounds__(256) void k_hist(const int* __restrict__ ei,
                                              int* __restrict__ hist, int E,
                                              int N, int NBLK,
                                              const int* __restrict__ flag) {
  __shared__ int lh[1024];
  int tid = threadIdx.x;
  int P = (N + BSZ - 1) >> BSHIFT;
  for (int i = tid; i < P; i += 256) lh[i] = 0;
  __syncthreads();
  int is64 = *flag;
  int e0 = blockIdx.x * CHUNK;
  int e1 = min(e0 + CHUNK, E);
  for (int e = e0 + tid; e < e1; e += 256) {
    int d = eload(ei, E + e, is64);
    atomicAdd(&lh[d >> BSHIFT], 1);
  }
  __syncthreads();
  for (int b = tid; b < P; b += 256) hist[b * NBLK + blockIdx.x] = lh[b];
}

// ---- generic 2-level exclusive scan (1024 elems / block) ----
__global__ __launch_bounds__(256) void k_scanA(const int* __restrict__ in,
                                               int* __restrict__ out,
                                               int* __restrict__ bsum, int n) {
  __shared__ int sh[256];
  int tid = threadIdx.x;
  int base = blockIdx.x * 1024 + tid * 4;
  int v0 = (base + 0 < n) ? in[base + 0] : 0;
  int v1 = (base + 1 < n) ? in[base + 1] : 0;
  int v2 = (base + 2 < n) ? in[base + 2] : 0;
  int v3 = (base + 3 < n) ? in[base + 3] : 0;
  int tsum = v0 + v1 + v2 + v3;
  sh[tid] = tsum;
  __syncthreads();
  for (int o = 1; o < 256; o <<= 1) {
    int x = (tid >= o) ? sh[tid - o] : 0;
    __syncthreads();
    sh[tid] += x;
    __syncthreads();
  }
  int excl = sh[tid] - tsum;
  if (base + 0 < n) out[base + 0] = excl;
  if (base + 1 < n) out[base + 1] = excl + v0;
  if (base + 2 < n) out[base + 2] = excl + v0 + v1;
  if (base + 3 < n) out[base + 3] = excl + v0 + v1 + v2;
  if (tid == 255) bsum[blockIdx.x] = sh[255];
}

// exclusive scan of up to 1024 block sums, in place (4 per thread)
__global__ __launch_bounds__(256) void k_scanB(int* __restrict__ bsum, int NB) {
  __shared__ int sh[256];
  int tid = threadIdx.x;
  int base = tid * 4;
  int v0 = (base + 0 < NB) ? bsum[base + 0] : 0;
  int v1 = (base + 1 < NB) ? bsum[base + 1] : 0;
  int v2 = (base + 2 < NB) ? bsum[base + 2] : 0;
  int v3 = (base + 3 < NB) ? bsum[base + 3] : 0;
  int tsum = v0 + v1 + v2 + v3;
  sh[tid] = tsum;
  __syncthreads();
  for (int o = 1; o < 256; o <<= 1) {
    int x = (tid >= o) ? sh[tid - o] : 0;
    __syncthreads();
    sh[tid] += x;
    __syncthreads();
  }
  int excl = sh[tid] - tsum;
  if (base + 0 < NB) bsum[base + 0] = excl;
  if (base + 1 < NB) bsum[base + 1] = excl + v0;
  if (base + 2 < NB) bsum[base + 2] = excl + v0 + v1;
  if (base + 3 < NB) bsum[base + 3] = excl + v0 + v1 + v2;
}

__global__ __launch_bounds__(256) void k_scanC(int* __restrict__ out,
                                               const int* __restrict__ bsum,
                                               int n, int total) {
  int i = blockIdx.x * 256 + threadIdx.x;
  if (i == 0) out[n] = total;
  if (i < n) out[i] += bsum[i >> 10];
}

// scatter edges into bucket-partitioned `pairs`, packed (src<<BSHIFT)|dst_lo.
__global__ __launch_bounds__(256) void k_scatter(const int* __restrict__ ei,
                                                 const int* __restrict__ histoff,
                                                 int* __restrict__ pairs, int E,
                                                 int N, int NBLK,
                                                 const int* __restrict__ flag) {
  __shared__ int lcur[1024];
  int tid = threadIdx.x;
  int P = (N + BSZ - 1) >> BSHIFT;
  for (int b = tid; b < P; b += 256)
    lcur[b] = histoff[b * NBLK + blockIdx.x];
  __syncthreads();
  int is64 = *flag;
  int e0 = blockIdx.x * CHUNK;
  int e1 = min(e0 + CHUNK, E);
  for (int e = e0 + tid; e < e1; e += 256) {
    int s = eload(ei, e, is64);
    int d = eload(ei, E + e, is64);
    int pos = atomicAdd(&lcur[d >> BSHIFT], 1);
    pairs[pos] = (s << BSHIFT) | (d & (BSZ - 1));
  }
}

// ---------------------------------------------------------------------------
// Fused per-bucket build: degree count -> 128-wide local exclusive scan ->
// off[] + dis[] -> CSR fill -> (folded) xsh = fp16(x * dis) for own rows.
// Offsets are bucket-local: base = histoff[b*NBLK].
// ---------------------------------------------------------------------------
__global__ __launch_bounds__(256) void k_build_bucket(
    const int* __restrict__ pairs, const int* __restrict__ histoff,
    int* __restrict__ off, float* __restrict__ dis, int* __restrict__ csr,
    const float* __restrict__ x, __half* __restrict__ xsh, int E, int N,
    int NBLK, int P) {
  __shared__ int lc[BSZ];
  __shared__ int lscan[BSZ];
  __shared__ int lcur[BSZ];
  __shared__ float ldis[BSZ];
  int tid = threadIdx.x;
  int b = blockIdx.x;
  if (tid < BSZ) lc[tid] = 0;
  __syncthreads();
  int s0 = histoff[b * NBLK];
  int s1 = histoff[(b + 1) * NBLK];
  for (int i = s0 + tid; i < s1; i += 256)
    atomicAdd(&lc[pairs[i] & (BSZ - 1)], 1);
  __syncthreads();
  if (tid < BSZ) lscan[tid] = lc[tid];
  __syncthreads();
#pragma unroll
  for (int o = 1; o < BSZ; o <<= 1) {
    int v = 0;
    if (tid < BSZ && tid >= o) v = lscan[tid - o];
    __syncthreads();
    if (tid < BSZ) lscan[tid] += v;
    __syncthreads();
  }
  int node = (b << BSHIFT) + tid;
  if (tid < BSZ) {
    int o_node = s0 + lscan[tid] - lc[tid];  // exclusive
    lcur[tid] = o_node;
    float d = rsqrtf((float)(lc[tid] + 1));  // +1 self loop
    ldis[tid] = d;
    if (node < N) {
      off[node] = o_node;
      dis[node] = d;
    }
  }
  if (b == P - 1 && tid == 0) off[N] = E;
  __syncthreads();
  // CSR fill
  for (int i = s0 + tid; i < s1; i += 256) {
    int pk = pairs[i];
    int pos = atomicAdd(&lcur[pk & (BSZ - 1)], 1);
    csr[pos] = pk >> BSHIFT;
  }
  // folded scale: xsh[row] = fp16(x[row]*dis[row]) for this bucket's rows
  for (int t = tid; t < BSZ * 16; t += 256) {
    int rl = t >> 4, q = t & 15;
    int row = (b << BSHIFT) + rl;
    if (row < N) {
      float d = ldis[rl];
      float4 v = *(const float4*)&x[(size_t)row * 64 + q * 4];
      union { uint2 u; __half2 h[2]; } pk;
      pk.h[0] = __floats2half2_rn(v.x * d, v.y * d);
      pk.h[1] = __floats2half2_rn(v.z * d, v.w * d);
      *(uint2*)&xsh[(size_t)row * 64 + q * 4] = pk.u;
    }
  }
}

__device__ __forceinline__ float gelu_exact(float v) {
  return 0.5f * v * (1.0f + erff(v * 0.70710678118654752440f));
}

// ---------------------------------------------------------------------------
// MFMA GEMM (fp16 in, fp32 acc, fp16 out). 256 thr = 4 waves x 16 rows.
// W staged fp16 fragment-major in LDS (frag*1KB + lane*16B, conflict-free
// ds_read_b128). A frags from global. Layouts per m89/m97:
// A row=l&15, k=8*(l>>4)+e; D col=l&15, row=4*(l>>4)+reg.
// EPI=0: out = (X@W)*dis[row]; EPI=1: out = gelu((X@W)+bias).
// ---------------------------------------------------------------------------
template <int K, int M, int EPI>
__global__ __launch_bounds__(256) void k_gemm5(
    const __half* __restrict__ X, const float* __restrict__ W,
    const float* __restrict__ dis, const float* __restrict__ bias,
    __half* __restrict__ G, int N) {
  constexpr int NT = M / 16;   // n-tiles
  constexpr int KK = K / 32;   // k-steps
  __shared__ _Float16 WtL[M * K];  // fragment-major

  int tid = threadIdx.x;
  for (int t = tid; t < M * K / 8; t += 256) {
    int l = t & 63;
    int fid = t >> 6;
    int nt = fid / KK, kk = fid % KK;
    int n = nt * 16 + (l & 15);
    int k0 = kk * 32 + (l >> 4) * 8;
    half8 h;
#pragma unroll
    for (int e = 0; e < 8; e++)
      h[e] = (_Float16)W[(size_t)(k0 + e) * M + n];
    *(half8*)&WtL[(size_t)t * 8] = h;
  }
  __syncthreads();

  int wave = tid >> 6, l = tid & 63;
  int lr = l & 15, lg = l >> 4;
  int row0 = blockIdx.x * 64 + wave * 16;

  half8 a[KK];
  {
    int row = min(row0 + lr, N - 1);
    const __half* xp = X + (size_t)row * K + lg * 8;
#pragma unroll
    for (int kk = 0; kk < KK; kk++)
      a[kk] = *(const half8*)(xp + kk * 32);
  }

  floatx4 acc[NT];
#pragma unroll
  for (int nt = 0; nt < NT; nt++) acc[nt] = {0.f, 0.f, 0.f, 0.f};

#pragma unroll
  for (int nt = 0; nt < NT; nt++) {
#pragma unroll
    for (int kk = 0; kk < KK; kk++) {
      half8 b = *(const half8*)&WtL[(size_t)((nt * KK + kk) * 64 + l) * 8];
      acc[nt] = __builtin_amdgcn_mfma_f32_16x16x32_f16(a[kk], b, acc[nt], 0, 0, 0);
    }
  }

#pragma unroll
  for (int r = 0; r < 4; r++) {
    int row = row0 + lg * 4 + r;
    if (row < N) {
      float dd = (EPI == 0) ? dis[row] : 0.f;
#pragma unroll
      for (int nt = 0; nt < NT; nt++) {
        int col = nt * 16 + lr;
        float v = acc[nt][r];
        if constexpr (EPI == 0) v *= dd;
        else v = gelu_exact(v + bias[col]);
        G[(size_t)row * M + col] = __float2half(v);
      }
    }
  }
}

__device__ __forceinline__ void acc8(float* a, uint4 r) {
  const __half2* h = reinterpret_cast<const __half2*>(&r);
#pragma unroll
  for (int q = 0; q < 4; q++) {
    float2 f = __half22float2(h[q]);
    a[2 * q] += f.x;
    a[2 * q + 1] += f.y;
  }
}

// ---------------------------------------------------------------------------
// fp16-table aggregation: 8 halves (16B) per lane, LPN = D/8 lanes per node,
// NPW = 64/LPN nodes per wave. fp32 accumulate. F16OUT: fp16 output buffer.
// ---------------------------------------------------------------------------
template <int D, bool HAS_BIAS, bool HAS_GELU, bool F16OUT>
__global__ __launch_bounds__(256) void k_agg(
    const __half* __restrict__ g, const int* __restrict__ off,
    const int* __restrict__ csr, const float* __restrict__ dis,
    const float* __restrict__ bias, void* __restrict__ outv, int N) {
  constexpr int LPN = D / 8;     // lanes per node (16B of halves each)
  constexpr int NPW = 64 / LPN;  // nodes per wave
  int wave = (blockIdx.x * 256 + threadIdx.x) >> 6;
  int lane = threadIdx.x & 63;
  int sub = lane / LPN;
  int sl = lane % LPN;
  int node = wave * NPW + sub;
  if (node >= N) return;
  const uint4* G16 = (const uint4*)g;
  float a[8];
#pragma unroll
  for (int q = 0; q < 8; q++) a[q] = 0.f;
  acc8(a, G16[(size_t)node * LPN + sl]);  // self loop
  int beg = off[node], end = off[node + 1];
  int j = beg;
  for (; j + 4 <= end; j += 4) {
    int s0 = csr[j], s1 = csr[j + 1], s2 = csr[j + 2], s3 = csr[j + 3];
    uint4 r0 = G16[(size_t)s0 * LPN + sl];
    uint4 r1 = G16[(size_t)s1 * LPN + sl];
    uint4 r2 = G16[(size_t)s2 * LPN + sl];
    uint4 r3 = G16[(size_t)s3 * LPN + sl];
    acc8(a, r0);
    acc8(a, r1);
    acc8(a, r2);
    acc8(a, r3);
  }
  for (; j < end; j++) acc8(a, G16[(size_t)csr[j] * LPN + sl]);
  float dd = dis[node];
  int c0 = sl * 8;
  float v[8];
#pragma unroll
  for (int q = 0; q < 8; q++) v[q] = a[q] * dd;
  if constexpr (HAS_BIAS) {
    float4 b0 = *(const float4*)&bias[c0];
    float4 b1 = *(const float4*)&bias[c0 + 4];
    v[0] += b0.x; v[1] += b0.y; v[2] += b0.z; v[3] += b0.w;
    v[4] += b1.x; v[5] += b1.y; v[6] += b1.z; v[7] += b1.w;
  }
  if constexpr (HAS_GELU) {
#pragma unroll
    for (int q = 0; q < 8; q++) v[q] = gelu_exact(v[q]);
  }
  if constexpr (F16OUT) {
    union { uint4 u; __half2 h[4]; } pk;
#pragma unroll
    for (int q = 0; q < 4; q++)
      pk.h[q] = __floats2half2_rn(v[2 * q], v[2 * q + 1]);
    *(uint4*)&((__half*)outv)[(size_t)node * D + c0] = pk.u;
  } else {
    float* out = (float*)outv;
    float4 o0 = {v[0], v[1], v[2], v[3]};
    float4 o1 = {v[4], v[5], v[6], v[7]};
    *(float4*)&out[(size_t)node * D + c0] = o0;
    *(float4*)&out[(size_t)node * D + c0 + 4] = o1;
  }
}

extern "C" void kernel_launch(void* const* d_in, const int* in_sizes, int n_in,
                              void* d_out, int out_size, void* d_ws,
                              size_t ws_size, hipStream_t stream) {
  const float* x = (const float*)d_in[0];
  const int* ei = (const int*)d_in[1];
  const float* W1 = (const float*)d_in[2];
  const float* b1 = (const float*)d_in[3];
  const float* W2 = (const float*)d_in[4];
  const float* b2 = (const float*)d_in[5];
  const float* W3 = (const float*)d_in[6];
  const float* b3 = (const float*)d_in[7];
  float* out = (float*)d_out;

  const int N = in_sizes[0] / 64;
  const int E = in_sizes[1] / 2;

  const int NBLK = (E + CHUNK - 1) / CHUNK;
  const int P = (N + BSZ - 1) >> BSHIFT;
  const int HT = P * NBLK;

  char* p = (char*)d_ws;
  auto alloc = [&](size_t bytes) {
    char* r = p;
    p += (bytes + 255) & ~(size_t)255;
    return r;
  };
  float* dis = (float*)alloc((size_t)N * 4);
  int* off = (int*)alloc((size_t)(N + 1) * 4);
  int* bsumH = (int*)alloc(4096);
  int* flag = (int*)alloc(256);
  int* hist = (int*)alloc((size_t)(HT + 1) * 4);
  int* histoff = (int*)alloc((size_t)(HT + 1) * 4);
  int* pairs = (int*)alloc((size_t)E * 4);
  int* csr = (int*)alloc((size_t)E * 4);
  __half* xsh = (__half*)alloc((size_t)N * 64 * 2);   // gather table L1
  __half* Xa_h = (__half*)alloc((size_t)N * 64 * 2);  // agg1 out / gemm1 in
  __half* h1_h = (__half*)alloc((size_t)N * 128 * 2); // gemm1 out / gemm2 in
  __half* gh = (__half*)alloc((size_t)N * 128 * 2);   // gemm2 out = table L2
  __half* h2_h = (__half*)alloc((size_t)N * 128 * 2); // agg2 out / gemm3 in
  __half* gh2 = (__half*)alloc((size_t)N * 64 * 2);   // gemm3 out = table L3

  const int NBH = (HT + 1023) / 1024;  // <= 1024 supported by k_scanB

  k_detect<<<1, 256, 0, stream>>>(ei, flag);
  k_hist<<<NBLK, 256, 0, stream>>>(ei, hist, E, N, NBLK, flag);
  k_scanA<<<NBH, 256, 0, stream>>>(hist, histoff, bsumH, HT);
  k_scanB<<<1, 256, 0, stream>>>(bsumH, NBH);
  k_scanC<<<(HT + 255) / 256, 256, 0, stream>>>(histoff, bsumH, HT, E);
  k_scatter<<<NBLK, 256, 0, stream>>>(ei, histoff, pairs, E, N, NBLK, flag);
  k_build_bucket<<<P, 256, 0, stream>>>(pairs, histoff, off, dis, csr, x, xsh,
                                        E, N, NBLK, P);

  const int gemm_blocks = (N + 63) / 64;    // 64 rows / block
  const int agg128_blocks = (N + 15) / 16;  // 4 nodes/wave, 4 waves/block
  const int agg64_blocks = (N + 31) / 32;   // 8 nodes/wave, 4 waves/block

  // layer 1 (swapped): Xa = agg(xsh); h1 = gelu(Xa@W1 + b1)
  k_agg<64, false, false, true><<<agg64_blocks, 256, 0, stream>>>(
      xsh, off, csr, dis, nullptr, (void*)Xa_h, N);
  k_gemm5<64, 128, 1><<<gemm_blocks, 256, 0, stream>>>(Xa_h, W1, nullptr, b1,
                                                       h1_h, N);
  // layer 2: g = fp16((h1@W2)*dis); h2 = fp16(gelu(agg(g) + b2))
  k_gemm5<128, 128, 0><<<gemm_blocks, 256, 0, stream>>>(h1_h, W2, dis, nullptr,
                                                        gh, N);
  k_agg<128, true, true, true><<<agg128_blocks, 256, 0, stream>>>(
      gh, off, csr, dis, b2, (void*)h2_h, N);
  // layer 3: g = fp16((h2@W3)*dis); out = agg(g) + b3 (fp32)
  k_gemm5<128, 64, 0><<<gemm_blocks, 256, 0, stream>>>(h2_h, W3, dis, nullptr,
                                                       gh2, N);
  k_agg<64, true, false, false><<<agg64_blocks, 256, 0, stream>>>(
      gh2, off, csr, dis, b3, (void*)out, N);
}